// Round 18
// baseline (144.709 us; speedup 1.0000x reference)
//
#include <hip/hip_runtime.h>

#define B_    16
#define L_    2048
#define D1_   512
#define G_    2
#define V_    320
#define GV_   640
#define DG_   384
#define NROW_ 32768
#define OUT0_ ((size_t)B_ * L_ * G_ * DG_)
#define WS_BYTES_ ((size_t)GV_ * D1_ * 2u)        // 655360: W bf16 frag plane
#define LG_OFF_SH_  ((size_t)GV_ * D1_)           // shorts: bf16 logits after W plane
#define SPLIT3_WS_  ((LG_OFF_SH_ + (size_t)NROW_ * GV_) * 2u)  // 42,598,400 bytes
#define THR_  2e-2f
#define GPAD_ 324

typedef __attribute__((ext_vector_type(8))) short          s16x8;
typedef __attribute__((ext_vector_type(4))) float          f32x4;
typedef __attribute__((ext_vector_type(4))) int            s32x4;
typedef __attribute__((ext_vector_type(4))) unsigned short u16x4;

__device__ __forceinline__ unsigned short f2bf(float x) {
    unsigned u = __float_as_uint(x);
    u += 0x7fffu + ((u >> 16) & 1u);
    return (unsigned short)(u >> 16);
}
__device__ __forceinline__ float bf2f(unsigned short h) {
    return __uint_as_float(((unsigned)h) << 16);
}
__device__ __forceinline__ unsigned cvtpk(float lo, float hi) {
    unsigned r;
    asm("v_cvt_pk_bf16_f32 %0, %1, %2" : "=v"(r) : "v"(lo), "v"(hi));
    return r;
}
union PU { unsigned u[4]; s16x8 v; };
__device__ __forceinline__ s16x8 pack8(const float4& a, const float4& b) {
    PU p;
    p.u[0] = cvtpk(a.x, a.y); p.u[1] = cvtpk(a.z, a.w);
    p.u[2] = cvtpk(b.x, b.y); p.u[3] = cvtpk(b.z, b.w);
    return p.v;
}
__device__ __forceinline__ s16x8 pack8v(const f32x4& a, const f32x4& b) {
    PU p;
    p.u[0] = cvtpk(a[0], a[1]); p.u[1] = cvtpk(a[2], a[3]);
    p.u[2] = cvtpk(b[0], b[1]); p.u[3] = cvtpk(b[2], b[3]);
    return p.v;
}
__device__ __forceinline__ void merge2(float& m1, int& i1, float& m2, int& i2,
                                       float om1, int oi1, float om2, int oi2) {
    if (om1 > m1 || (om1 == m1 && oi1 < i1)) {
        if (m1 > om2 || (m1 == om2 && i1 < oi2)) { m2 = m1; i2 = i1; }
        else                                     { m2 = om2; i2 = oi2; }
        m1 = om1; i1 = oi1;
    } else if (om1 > m2 || (om1 == m2 && oi1 < i2)) { m2 = om1; i2 = oi1; }
}

// ============ prep: W frag plane only (coalesced: wave = one 1KB tile, slot==lane) ======
__global__ void prep_w_kernel(const float* __restrict__ W, unsigned short* __restrict__ wsW) {
    const int bw = threadIdx.x >> 6, l = threadIdx.x & 63;
    int t = blockIdx.x * 4 + bw;             // 0..639
    int o   = (t >> 4) * 16 + (l & 15);
    int col = (t & 15) * 32 + (l >> 4) * 8;
    const float* src = W + ((size_t)o << 9) + col;
    f32x4 a = *(const f32x4*)(src);
    f32x4 b = *(const f32x4*)(src + 4);
    *(s16x8*)(wsW + ((size_t)t << 9) + (l << 3)) = pack8v(a, b);
}

// ============ K1: barrier-free, LDS-free GEMM; A read DIRECTLY from fp32 hidden ========
// (frag slot mapping is identity -> lane's A-frag = hidden[chunk*16+(l&15)][kk*32+(l>>4)*8..+8],
//  coalesced 128B/row; packed in-loop with v_cvt_pk_bf16_f32). 1024 blocks, XCD-swizzled
// so the 4 ct-blocks of one mt share an XCD (hidden fetched once from HBM, 3 L2 hits).
__global__ __launch_bounds__(512, 4) void k1_gemm(
    const unsigned short* __restrict__ wsW,
    const float* __restrict__ hidden,
    const float* __restrict__ bias,
    unsigned short* __restrict__ lgout)
{
    const int tid = threadIdx.x;
    const int w = tid >> 6, lane = tid & 63;
    const int rg = w >> 1, cg = w & 1;
    const int q = lane >> 4, c = lane & 15;
    const int d = blockIdx.x;
    const int mt = (d & 7) * 32 + (d >> 5);
    const int ct = (d >> 3) & 3;

    // A direct addressing: two 16-row chunks per wave (rf = 0,1)
    const float* aR0 = hidden + ((size_t)(mt * 128 + rg * 32 + (lane & 15)) << 9) + ((lane >> 4) << 3);
    const float* aR1 = aR0 + ((size_t)16 << 9);
    const unsigned short* wp = wsW + ((size_t)(ct * 10 + cg * 5) << 13) + (lane << 3);

    f32x4 acc0[5], acc1[5];
#pragma unroll
    for (int cf = 0; cf < 5; ++cf) { acc0[cf] = (f32x4){0,0,0,0}; acc1[cf] = (f32x4){0,0,0,0}; }

    f32x4 Ar0a, Ar0b, Ar1a, Ar1b;
    f32x4 Br0a, Br0b, Br1a, Br1b;
    s16x8 wf0, wf1, wf2, wf3, wf4, fa0, fa1;

#define LDA(S, KK) { \
        S##r0a = *(const f32x4*)(aR0 + (KK) * 32); \
        S##r0b = *(const f32x4*)(aR0 + (KK) * 32 + 4); \
        S##r1a = *(const f32x4*)(aR1 + (KK) * 32); \
        S##r1b = *(const f32x4*)(aR1 + (KK) * 32 + 4); }
#define LDW(KK) { \
        wf0 = *(const s16x8*)(wp + 0 * 8192 + (KK) * 512); \
        wf1 = *(const s16x8*)(wp + 1 * 8192 + (KK) * 512); \
        wf2 = *(const s16x8*)(wp + 2 * 8192 + (KK) * 512); \
        wf3 = *(const s16x8*)(wp + 3 * 8192 + (KK) * 512); \
        wf4 = *(const s16x8*)(wp + 4 * 8192 + (KK) * 512); }
#define CVT(S) { fa0 = pack8v(S##r0a, S##r0b); fa1 = pack8v(S##r1a, S##r1b); }
#define MM() { \
        acc0[0] = __builtin_amdgcn_mfma_f32_16x16x32_bf16(fa0, wf0, acc0[0], 0, 0, 0); \
        acc1[0] = __builtin_amdgcn_mfma_f32_16x16x32_bf16(fa1, wf0, acc1[0], 0, 0, 0); \
        acc0[1] = __builtin_amdgcn_mfma_f32_16x16x32_bf16(fa0, wf1, acc0[1], 0, 0, 0); \
        acc1[1] = __builtin_amdgcn_mfma_f32_16x16x32_bf16(fa1, wf1, acc1[1], 0, 0, 0); \
        acc0[2] = __builtin_amdgcn_mfma_f32_16x16x32_bf16(fa0, wf2, acc0[2], 0, 0, 0); \
        acc1[2] = __builtin_amdgcn_mfma_f32_16x16x32_bf16(fa1, wf2, acc1[2], 0, 0, 0); \
        acc0[3] = __builtin_amdgcn_mfma_f32_16x16x32_bf16(fa0, wf3, acc0[3], 0, 0, 0); \
        acc1[3] = __builtin_amdgcn_mfma_f32_16x16x32_bf16(fa1, wf3, acc1[3], 0, 0, 0); \
        acc0[4] = __builtin_amdgcn_mfma_f32_16x16x32_bf16(fa0, wf4, acc0[4], 0, 0, 0); \
        acc1[4] = __builtin_amdgcn_mfma_f32_16x16x32_bf16(fa1, wf4, acc1[4], 0, 0, 0); }

    LDA(A, 0)
#pragma unroll 1
    for (int kp = 0; kp < 8; ++kp) {
        LDW(2 * kp)
        CVT(A)
        LDA(B, 2 * kp + 1)
        MM()
        LDW(2 * kp + 1)
        CVT(B)
        if (kp < 7) LDA(A, 2 * kp + 2)
        MM()
    }
#undef LDA
#undef LDW
#undef CVT
#undef MM

    float bv[5];
#pragma unroll
    for (int cf = 0; cf < 5; ++cf) bv[cf] = bias[ct * 160 + cg * 80 + cf * 16 + c];
#pragma unroll
    for (int rf = 0; rf < 2; ++rf) {
        size_t mrow = (size_t)mt * 128 + rg * 32 + rf * 16 + q * 4;
        unsigned short* op = lgout + mrow * GV_ + ct * 160 + cg * 80 + c;
        const f32x4* ac = rf ? acc1 : acc0;
#pragma unroll
        for (int cf = 0; cf < 5; ++cf)
#pragma unroll
            for (int r = 0; r < 4; ++r)
                op[(size_t)r * GV_ + cf * 16] = f2bf(ac[cf][r] + bv[cf]);
    }
}

// ============ K2: 2048 blocks (one l) x 256 thr (4 waves). Wave = 4 b-rows. ============
__global__ __launch_bounds__(256, 4) void k2_epi(
    const float* __restrict__ hidden,
    const float* __restrict__ W,
    const float* __restrict__ bias,
    const float* __restrict__ cb,
    const float* __restrict__ gn,
    const unsigned short* __restrict__ lgb,
    float* __restrict__ out)
{
    __shared__ float PERPW[4][GV_];    // 10.2 KB
    const int tid = threadIdx.x;
    const int w = tid >> 6, lane = tid & 63;
    const int h = lane >> 5, k = lane & 31;
    const int l = blockIdx.x;

    f32x4 pac0 = {0,0,0,0}, pac1 = {0,0,0,0}, pac2 = {0,0,0,0};

    f32x4 Alg0, Alg1, Alg2, Agv0, Agv1, Agv2;
    f32x4 Blg0, Blg1, Blg2, Bgv0, Bgv1, Bgv2;

#define NTL(p) __builtin_nontemporal_load((const f32x4*)(p))
#define LOADROW(S, RR) { \
        size_t row_ = ((size_t)(w * 4 + (RR))) * L_ + l; \
        const unsigned short* lrb = lgb + row_ * GV_ + h * V_ + (k << 2); \
        const float* grb = gn + row_ * GV_ + h * V_ + (k << 2); \
        u16x4 L0 = *(const u16x4*)(lrb); \
        u16x4 L1 = *(const u16x4*)(lrb + 128); \
        S##gv0 = NTL(grb); S##gv1 = NTL(grb + 128); \
        _Pragma("unroll") \
        for (int j = 0; j < 4; ++j) { S##lg0[j] = bf2f(L0[j]); S##lg1[j] = bf2f(L1[j]); } \
        if (k < 16) { \
            u16x4 L2 = *(const u16x4*)(lrb + 256); \
            S##gv2 = NTL(grb + 256); \
            _Pragma("unroll") \
            for (int j = 0; j < 4; ++j) S##lg2[j] = bf2f(L2[j]); \
        } }

#define EXACT(CI, EN) { \
        if (EN) { \
            const int ci_ = (CI); \
            const float* ar_ = hidden + row_ * D1_ + (k << 4); \
            const float* wr_ = W + (size_t)(h * V_ + ci_) * D1_ + (k << 4); \
            double s_ = 0.0; \
            _Pragma("unroll 4") \
            for (int j = 0; j < 16; ++j) s_ = fma((double)ar_[j], (double)wr_[j], s_); \
            _Pragma("unroll") \
            for (int off = 1; off <= 16; off <<= 1) s_ += __shfl_xor(s_, off); \
            s_ += (double)bias[h * V_ + ci_] + (double)gn[row_ * GV_ + h * V_ + ci_]; \
            if (s_ > bestv || (s_ == bestv && ci_ < bi)) { bestv = s_; bi = ci_; } \
        } }

#define PROCROW(S, RR) { \
        const size_t row_ = ((size_t)(w * 4 + (RR))) * L_ + l; \
        _Pragma("unroll") \
        for (int j = 0; j < 4; ++j) { S##gv0[j] += S##lg0[j]; S##gv1[j] += S##lg1[j]; } \
        if (k < 16) { _Pragma("unroll") for (int j = 0; j < 4; ++j) S##gv2[j] += S##lg2[j]; } \
        float m1 = -3e38f; \
        _Pragma("unroll") \
        for (int j = 0; j < 4; ++j) { m1 = fmaxf(m1, S##gv0[j]); m1 = fmaxf(m1, S##gv1[j]); } \
        if (k < 16) { _Pragma("unroll") for (int j = 0; j < 4; ++j) m1 = fmaxf(m1, S##gv2[j]); } \
        _Pragma("unroll") \
        for (int mk = 1; mk <= 16; mk <<= 1) m1 = fmaxf(m1, __shfl_xor(m1, mk)); \
        int li = 0x7fffffff; \
        _Pragma("unroll") \
        for (int j = 0; j < 4; ++j) { \
            if (S##gv0[j] == m1) li = min(li, (k << 2) + j); \
            if (S##gv1[j] == m1) li = min(li, ((k + 32) << 2) + j); } \
        if (k < 16) { _Pragma("unroll") for (int j = 0; j < 4; ++j) if (S##gv2[j] == m1) li = min(li, ((k + 64) << 2) + j); } \
        _Pragma("unroll") \
        for (int mk = 1; mk <= 16; mk <<= 1) li = min(li, __shfl_xor(li, mk)); \
        const int i1 = li; \
        float m2 = -3e38f; \
        _Pragma("unroll") \
        for (int j = 0; j < 4; ++j) { \
            if (((k << 2) + j) != i1)        m2 = fmaxf(m2, S##gv0[j]); \
            if ((((k + 32) << 2) + j) != i1) m2 = fmaxf(m2, S##gv1[j]); } \
        if (k < 16) { _Pragma("unroll") for (int j = 0; j < 4; ++j) if ((((k + 64) << 2) + j) != i1) m2 = fmaxf(m2, S##gv2[j]); } \
        _Pragma("unroll") \
        for (int mk = 1; mk <= 16; mk <<= 1) m2 = fmaxf(m2, __shfl_xor(m2, mk)); \
        float se = 0.f; \
        _Pragma("unroll") \
        for (int j = 0; j < 4; ++j) { \
            S##lg0[j] = __expf(S##lg0[j]); se += S##lg0[j]; \
            S##lg1[j] = __expf(S##lg1[j]); se += S##lg1[j]; } \
        if (k < 16) { _Pragma("unroll") for (int j = 0; j < 4; ++j) { S##lg2[j] = __expf(S##lg2[j]); se += S##lg2[j]; } } \
        _Pragma("unroll") \
        for (int mk = 1; mk <= 16; mk <<= 1) se += __shfl_xor(se, mk); \
        const float inv = 1.0f / (se * 16.0f); \
        _Pragma("unroll") \
        for (int j = 0; j < 4; ++j) { pac0[j] += S##lg0[j] * inv; pac1[j] += S##lg1[j] * inv; } \
        if (k < 16) { _Pragma("unroll") for (int j = 0; j < 4; ++j) pac2[j] += S##lg2[j] * inv; } \
        int idx = i1; \
        if (m1 - m2 < THR_) { \
            int li2 = 0x7fffffff; \
            _Pragma("unroll") \
            for (int j = 0; j < 4; ++j) { \
                int v0 = (k << 2) + j;        if (v0 != i1 && S##gv0[j] == m2) li2 = min(li2, v0); \
                int v1 = ((k + 32) << 2) + j; if (v1 != i1 && S##gv1[j] == m2) li2 = min(li2, v1); } \
            if (k < 16) { _Pragma("unroll") for (int j = 0; j < 4; ++j) { int v2 = ((k + 64) << 2) + j; if (v2 != i1 && S##gv2[j] == m2) li2 = min(li2, v2); } } \
            _Pragma("unroll") \
            for (int mk = 1; mk <= 16; mk <<= 1) li2 = min(li2, __shfl_xor(li2, mk)); \
            const int i2 = li2; \
            float m3 = -3e38f; \
            _Pragma("unroll") \
            for (int j = 0; j < 4; ++j) { \
                int v0 = (k << 2) + j;        if (v0 != i1 && v0 != i2) m3 = fmaxf(m3, S##gv0[j]); \
                int v1 = ((k + 32) << 2) + j; if (v1 != i1 && v1 != i2) m3 = fmaxf(m3, S##gv1[j]); } \
            if (k < 16) { _Pragma("unroll") for (int j = 0; j < 4; ++j) { int v2 = ((k + 64) << 2) + j; if (v2 != i1 && v2 != i2) m3 = fmaxf(m3, S##gv2[j]); } } \
            _Pragma("unroll") \
            for (int mk = 1; mk <= 16; mk <<= 1) m3 = fmaxf(m3, __shfl_xor(m3, mk)); \
            int li3 = 0x7fffffff; \
            _Pragma("unroll") \
            for (int j = 0; j < 4; ++j) { \
                int v0 = (k << 2) + j;        if (v0 != i1 && v0 != i2 && S##gv0[j] == m3) li3 = min(li3, v0); \
                int v1 = ((k + 32) << 2) + j; if (v1 != i1 && v1 != i2 && S##gv1[j] == m3) li3 = min(li3, v1); } \
            if (k < 16) { _Pragma("unroll") for (int j = 0; j < 4; ++j) { int v2 = ((k + 64) << 2) + j; if (v2 != i1 && v2 != i2 && S##gv2[j] == m3) li3 = min(li3, v2); } } \
            _Pragma("unroll") \
            for (int mk = 1; mk <= 16; mk <<= 1) li3 = min(li3, __shfl_xor(li3, mk)); \
            const int i3 = li3; \
            double bestv = -1e300; int bi = 0; \
            EXACT(i1, true) \
            EXACT(i2, true) \
            EXACT(i3, (m1 - m3 < THR_)) \
            idx = bi; \
        } \
        { \
            const float* src = cb + (size_t)(h * V_ + idx) * DG_ + (k << 2); \
            float* dst = out + row_ * (G_ * DG_) + h * DG_ + (k << 2); \
            __builtin_nontemporal_store(*(const f32x4*)(src),       (f32x4*)(dst)); \
            __builtin_nontemporal_store(*(const f32x4*)(src + 128), (f32x4*)(dst + 128)); \
            __builtin_nontemporal_store(*(const f32x4*)(src + 256), (f32x4*)(dst + 256)); \
        } }

    LOADROW(A, 0)
    LOADROW(B, 1)
    PROCROW(A, 0)
    LOADROW(A, 2)
    PROCROW(B, 1)
    LOADROW(B, 3)
    PROCROW(A, 2)
    PROCROW(B, 3)
#undef NTL
#undef LOADROW
#undef EXACT
#undef PROCROW

    *(f32x4*)&PERPW[w][h * V_ + (k << 2)]        = pac0;
    *(f32x4*)&PERPW[w][h * V_ + ((k + 32) << 2)] = pac1;
    if (k < 16)
        *(f32x4*)&PERPW[w][h * V_ + ((k + 64) << 2)] = pac2;
    __syncthreads();

    if (tid < 160) {
        f32x4 s = *(const f32x4*)&PERPW[0][tid * 4];
#pragma unroll
        for (int ww = 1; ww < 4; ++ww) {
            f32x4 t = *(const f32x4*)&PERPW[ww][tid * 4];
#pragma unroll
            for (int j = 0; j < 4; ++j) s[j] += t[j];
        }
        __builtin_nontemporal_store(s, (f32x4*)(out + OUT0_ + (size_t)l * GV_ + tid * 4));
    }
}

// ============ Fallback: fused kernel (ws too small for split planes) ============
template<bool HAS_WS>
__global__ __launch_bounds__(512, 4) void gvq7_kernel(
    const float* __restrict__ hidden,
    const float* __restrict__ W,
    const float* __restrict__ bias,
    const float* __restrict__ cb,
    const float* __restrict__ gn,
    float* __restrict__ out,
    const unsigned short* __restrict__ ws)
{
    __shared__ float GLDS[32][GPAD_];
    __shared__ __align__(16) float pm1[4][64], pm2[4][64], plx[4][64], psum[4][64];
    __shared__ __align__(16) int   pi1[4][64], pi2[4][64];
    __shared__ int IDX[64];
    __shared__ int qn, qrow[64], qc1[64], qc2[64];

    const int tid  = threadIdx.x;
    const int w    = tid >> 6, lane = tid & 63;
    const int rg   = w >> 2, cg = w & 3;
    const int q    = lane >> 4, c = lane & 15;
    const int d    = blockIdx.x;
    const int g    = (d >> 3) & 1;
    const int lq   = (d >> 4) * 8 + (d & 7);
    const size_t lbase = (size_t)lq * 4;

    if (tid == 0) qn = 0;

    const int arow = lane & 15;
    const int kq8  = (lane >> 4) * 8;
    const float* aP0 = hidden + ((size_t)arow * L_ + lbase + rg * 2) * D1_ + kq8;
    const float* aP1 = aP0 + D1_;
    const unsigned short* wP = ws + (size_t)(g * 20 + cg * 5) * 8192 + (size_t)lane * 8;
    const float* wfP = W + ((size_t)(g * V_ + cg * 80 + arow)) * D1_ + kq8;

    const int srow = tid >> 4, t16 = tid & 15;
    const float* gnst = gn + (((size_t)(srow & 15) * L_ + lbase + ((srow >> 4) << 1)) * G_ + g) * V_
                           + (t16 << 2);

    f32x4 acc0[5], acc1[5];
#pragma unroll
    for (int cf = 0; cf < 5; ++cf) { acc0[cf] = (f32x4){0,0,0,0}; acc1[cf] = (f32x4){0,0,0,0}; }

    float4 Aa0, Aa1, Aa2, Aa3, Ba0, Ba1, Ba2, Ba3;
    s16x8 Aw0, Aw1, Aw2, Aw3, Aw4, Bw0, Bw1, Bw2, Bw3, Bw4;
    s16x8 fA0, fA1, fB0, fB1;

#define LDA(S, R) { S##a0 = *(const float4*)(aP0 + (R)*32);     S##a1 = *(const float4*)(aP0 + (R)*32 + 4); \
                    S##a2 = *(const float4*)(aP1 + (R)*32);     S##a3 = *(const float4*)(aP1 + (R)*32 + 4); }
#define LDW1(S, CF, R) { if (HAS_WS) { S##w##CF = *(const s16x8*)(wP + (CF)*8192 + (R)*512); } \
                         else { float4 x_ = *(const float4*)(wfP + (CF)*8192 + (R)*32); \
                                float4 y_ = *(const float4*)(wfP + (CF)*8192 + (R)*32 + 4); \
                                S##w##CF = pack8(x_, y_); } }
#define LDW(S, R) { LDW1(S,0,R) LDW1(S,1,R) LDW1(S,2,R) LDW1(S,3,R) LDW1(S,4,R) }
#define CVT(S) { f##S##0 = pack8(S##a0, S##a1); f##S##1 = pack8(S##a2, S##a3); }
#define MM1(S, CF) { acc0[CF] = __builtin_amdgcn_mfma_f32_16x16x32_bf16(f##S##0, S##w##CF, acc0[CF], 0, 0, 0); \
                     acc1[CF] = __builtin_amdgcn_mfma_f32_16x16x32_bf16(f##S##1, S##w##CF, acc1[CF], 0, 0, 0); }
#define MM(S) { MM1(S,0) MM1(S,1) MM1(S,2) MM1(S,3) MM1(S,4) }

    LDA(A, 0) LDW(A, 0)
#pragma unroll 1
    for (int kp = 0; kp < 8; ++kp) {
        CVT(A)
        LDA(B, 1) LDW(B, 1)
        MM(A)
        CVT(B)
        if (kp < 7) { LDA(A, 2) LDW(A, 2) }
        MM(B)
        aP0 += 64; aP1 += 64; wP += 1024; wfP += 64;
    }
#undef LDA
#undef LDW1
#undef LDW
#undef CVT
#undef MM1
#undef MM

    float bv[5];
#pragma unroll
    for (int cf = 0; cf < 5; ++cf) bv[cf] = bias[g * V_ + cg * 80 + cf * 16 + c];
#pragma unroll
    for (int cf = 0; cf < 5; ++cf)
#pragma unroll
        for (int r = 0; r < 4; ++r) { acc0[cf][r] += bv[cf]; acc1[cf][r] += bv[cf]; }

    auto scanrf = [&](const f32x4* a5, int rf) {
        float m1[4], m2[4], lx[4]; int i1[4], i2[4];
#pragma unroll
        for (int r = 0; r < 4; ++r) { m1[r] = -3e38f; m2[r] = -3e38f; lx[r] = -3e38f; i1[r] = 0; i2[r] = 0; }
#pragma unroll
        for (int cf = 0; cf < 5; ++cf) {
            const int col = cg * 80 + cf * 16 + c;
#pragma unroll
            for (int r = 0; r < 4; ++r) {
                float lg = a5[cf][r];
                float s  = lg + GLDS[rg * 16 + q * 4 + r][col];
                lx[r] = fmaxf(lx[r], lg);
                if (s > m1[r])      { m2[r] = m1[r]; i2[r] = i1[r]; m1[r] = s; i1[r] = col; }
                else if (s > m2[r]) { m2[r] = s; i2[r] = col; }
            }
        }
#pragma unroll
        for (int mk = 1; mk <= 8; mk <<= 1) {
#pragma unroll
            for (int r = 0; r < 4; ++r) {
                float om1 = __shfl_xor(m1[r], mk); int oi1 = __shfl_xor(i1[r], mk);
                float om2 = __shfl_xor(m2[r], mk); int oi2 = __shfl_xor(i2[r], mk);
                lx[r] = fmaxf(lx[r], __shfl_xor(lx[r], mk));
                merge2(m1[r], i1[r], m2[r], i2[r], om1, oi1, om2, oi2);
            }
        }
        if (c == 0) {
            int row0 = rg * 32 + rf * 16 + q * 4;
            *(f32x4*)&pm1[cg][row0] = (f32x4){m1[0], m1[1], m1[2], m1[3]};
            *(s32x4*)&pi1[cg][row0] = (s32x4){i1[0], i1[1], i1[2], i1[3]};
            *(f32x4*)&pm2[cg][row0] = (f32x4){m2[0], m2[1], m2[2], m2[3]};
            *(s32x4*)&pi2[cg][row0] = (s32x4){i2[0], i2[1], i2[2], i2[3]};
            *(f32x4*)&plx[cg][row0] = (f32x4){lx[0], lx[1], lx[2], lx[3]};
        }
    };

    {
        f32x4 gr[5];
#pragma unroll
        for (int j = 0; j < 5; ++j)
            gr[j] = __builtin_nontemporal_load((const f32x4*)(gnst + j * 64));
#pragma unroll
        for (int j = 0; j < 5; ++j)
            *(f32x4*)&GLDS[srow][(t16 << 2) + j * 64] = gr[j];
        __syncthreads();
        scanrf(acc0, 0);
        __syncthreads();
    }
    {
        f32x4 gr[5];
#pragma unroll
        for (int j = 0; j < 5; ++j)
            gr[j] = __builtin_nontemporal_load((const f32x4*)(gnst + GV_ + j * 64));
#pragma unroll
        for (int j = 0; j < 5; ++j)
            *(f32x4*)&GLDS[srow][(t16 << 2) + j * 64] = gr[j];
        __syncthreads();
        scanrf(acc1, 1);
        __syncthreads();
    }

    auto softrf = [&](f32x4* a5, int rf) {
        int row0 = rg * 32 + rf * 16 + q * 4;
        float LM[4], se[4];
#pragma unroll
        for (int r = 0; r < 4; ++r) {
            LM[r] = fmaxf(fmaxf(plx[0][row0 + r], plx[1][row0 + r]),
                          fmaxf(plx[2][row0 + r], plx[3][row0 + r]));
            se[r] = 0.f;
        }
#pragma unroll
        for (int cf = 0; cf < 5; ++cf)
#pragma unroll
            for (int r = 0; r < 4; ++r) {
                float e = __expf(a5[cf][r] - LM[r]);
                a5[cf][r] = e; se[r] += e;
            }
#pragma unroll
        for (int mk = 1; mk <= 8; mk <<= 1)
#pragma unroll
            for (int r = 0; r < 4; ++r) se[r] += __shfl_xor(se[r], mk);
        if (c == 0) *(f32x4*)&psum[cg][row0] = (f32x4){se[0], se[1], se[2], se[3]};
    };
    softrf(acc0, 0);
    softrf(acc1, 1);
    __syncthreads();

    auto perprf = [&](const f32x4* a5, int rf) {
        int row0 = rg * 32 + rf * 16 + q * 4;
        float IZ[4];
#pragma unroll
        for (int r = 0; r < 4; ++r)
            IZ[r] = 1.0f / ((psum[0][row0 + r] + psum[1][row0 + r]
                           + psum[2][row0 + r] + psum[3][row0 + r]) * 16.0f);
        size_t ob = OUT0_ + (lbase + rg * 2 + rf) * GV_ + g * V_ + cg * 80 + c;
#pragma unroll
        for (int cf = 0; cf < 5; ++cf) {
            float pp = a5[cf][0] * IZ[0] + a5[cf][1] * IZ[1]
                     + a5[cf][2] * IZ[2] + a5[cf][3] * IZ[3];
            pp += __shfl_xor(pp, 16); pp += __shfl_xor(pp, 32);
            if (q == 0) __builtin_nontemporal_store(pp, &out[ob + cf * 16]);
        }
    };
    perprf(acc0, 0);
    perprf(acc1, 1);

    if (tid < 64) {
        const int row = tid;
        float M1 = pm1[0][row]; int I1 = pi1[0][row];
        float M2 = pm2[0][row]; int I2 = pi2[0][row];
#pragma unroll
        for (int c2 = 1; c2 < 4; ++c2)
            merge2(M1, I1, M2, I2, pm1[c2][row], pi1[c2][row], pm2[c2][row], pi2[c2][row]);
        if (M1 - M2 >= 8e-3f) {
            IDX[row] = I1;
        } else {
            int s = atomicAdd(&qn, 1);
            qrow[s] = row; qc1[s] = I1; qc2[s] = I2;
        }
    }
    __syncthreads();

    {
        const int nq = qn;
        for (int qi = w; qi < nq; qi += 8) {
            const int row = qrow[qi];
            const int c1 = qc1[qi], c2 = qc2[qi];
            const int b = row & 15, li = row >> 4;
            const float* ar = hidden + ((size_t)b * L_ + lbase + li) * D1_ + lane * 8;
            const float* w1 = W + (size_t)(g * V_ + c1) * D1_ + lane * 8;
            const float* w2 = W + (size_t)(g * V_ + c2) * D1_ + lane * 8;
            double s1 = 0.0, s2 = 0.0;
#pragma unroll
            for (int j = 0; j < 8; ++j) {
                double a = (double)ar[j];
                s1 = fma(a, (double)w1[j], s1);
                s2 = fma(a, (double)w2[j], s2);
            }
#pragma unroll
            for (int off = 1; off < 64; off <<= 1) {
                s1 += __shfl_xor(s1, off);
                s2 += __shfl_xor(s2, off);
            }
            if (lane == 0) {
                const size_t gb = (((size_t)b * L_ + lbase + li) * G_ + g) * V_;
                s1 += (double)bias[g * V_ + c1] + (double)gn[gb + c1];
                s2 += (double)bias[g * V_ + c2] + (double)gn[gb + c2];
                IDX[row] = (s2 > s1 || (s2 == s1 && c2 < c1)) ? c2 : c1;
            }
        }
    }
    __syncthreads();

#pragma unroll 1
    for (int it = 0; it < 12; ++it) {
        int i = tid + it * 512;
        int row = i / 96, f = i - row * 96;
        int v = IDX[row];
        int b = row & 15, li = row >> 4;
        f32x4 val = *(const f32x4*)(cb + ((size_t)(g * V_ + v) * DG_) + f * 4);
        __builtin_nontemporal_store(val,
            (f32x4*)(out + ((size_t)b * L_ + lbase + li) * (G_ * DG_) + g * DG_ + f * 4));
    }
}

extern "C" void kernel_launch(void* const* d_in, const int* in_sizes, int n_in,
                              void* d_out, int out_size, void* d_ws, size_t ws_size,
                              hipStream_t stream) {
    const float* hidden   = (const float*)d_in[0];
    const float* W        = (const float*)d_in[1];
    const float* bias     = (const float*)d_in[2];
    const float* codebook = (const float*)d_in[3];
    const float* gumbel   = (const float*)d_in[4];
    float* out = (float*)d_out;

    if (ws_size >= SPLIT3_WS_) {
        unsigned short* wsW = (unsigned short*)d_ws;
        unsigned short* lgb = wsW + LG_OFF_SH_;
        prep_w_kernel<<<160, 256, 0, stream>>>(W, wsW);
        k1_gemm<<<1024, 512, 0, stream>>>(wsW, hidden, bias, lgb);
        k2_epi<<<2048, 256, 0, stream>>>(hidden, W, bias, codebook, gumbel, lgb, out);
    } else if (ws_size >= WS_BYTES_) {
        prep_w_kernel<<<160, 256, 0, stream>>>(W, (unsigned short*)d_ws);
        gvq7_kernel<true><<<1024, 512, 0, stream>>>(hidden, W, bias, codebook, gumbel, out,
                                                    (const unsigned short*)d_ws);
    } else {
        gvq7_kernel<false><<<1024, 512, 0, stream>>>(hidden, W, bias, codebook, gumbel, out,
                                                     (const unsigned short*)d_ws);
    }
}

// Round 19
// 109.867 us; speedup vs baseline: 1.3171x; 1.3171x over previous
//
#include <hip/hip_runtime.h>

#define B_    16
#define L_    2048
#define D1_   512
#define G_    2
#define V_    320
#define GV_   640
#define DG_   384
#define NROW_ 32768
#define OUT0_ ((size_t)B_ * L_ * G_ * DG_)
#define WS_BYTES_ ((size_t)GV_ * D1_ * 2u)        // 655360: W bf16 frag plane (fallback tier)
#define WSA_OFF_SH_ ((size_t)GV_ * D1_)           // shorts: A plane after W plane
#define LG_OFF_SH_  (WSA_OFF_SH_ + (size_t)NROW_ * D1_)   // shorts: bf16 logits after A
#define SPLIT2_WS_  ((LG_OFF_SH_ + (size_t)NROW_ * GV_) * 2u)  // 76,152,832 bytes
#define THR_  2e-2f
#define GPAD_ 324

typedef __attribute__((ext_vector_type(8))) short          s16x8;
typedef __attribute__((ext_vector_type(4))) float          f32x4;
typedef __attribute__((ext_vector_type(4))) int            s32x4;
typedef __attribute__((ext_vector_type(4))) unsigned short u16x4;

__device__ __forceinline__ unsigned short f2bf(float x) {
    unsigned u = __float_as_uint(x);
    u += 0x7fffu + ((u >> 16) & 1u);
    return (unsigned short)(u >> 16);
}
__device__ __forceinline__ float bf2f(unsigned short h) {
    return __uint_as_float(((unsigned)h) << 16);
}
__device__ __forceinline__ unsigned cvtpk(float lo, float hi) {
    unsigned r;
    asm("v_cvt_pk_bf16_f32 %0, %1, %2" : "=v"(r) : "v"(lo), "v"(hi));
    return r;
}
union PU { unsigned u[4]; s16x8 v; };
__device__ __forceinline__ s16x8 pack8(const float4& a, const float4& b) {
    PU p;
    p.u[0] = cvtpk(a.x, a.y); p.u[1] = cvtpk(a.z, a.w);
    p.u[2] = cvtpk(b.x, b.y); p.u[3] = cvtpk(b.z, b.w);
    return p.v;
}
__device__ __forceinline__ s16x8 pack8v(const f32x4& a, const f32x4& b) {
    PU p;
    p.u[0] = cvtpk(a[0], a[1]); p.u[1] = cvtpk(a[2], a[3]);
    p.u[2] = cvtpk(b[0], b[1]); p.u[3] = cvtpk(b[2], b[3]);
    return p.v;
}
__device__ __forceinline__ void merge2(float& m1, int& i1, float& m2, int& i2,
                                       float om1, int oi1, float om2, int oi2) {
    if (om1 > m1 || (om1 == m1 && oi1 < i1)) {
        if (m1 > om2 || (m1 == om2 && i1 < oi2)) { m2 = m1; i2 = i1; }
        else                                     { m2 = om2; i2 = oi2; }
        m1 = om1; i1 = oi1;
    } else if (om1 > m2 || (om1 == m2 && oi1 < i2)) { m2 = om1; i2 = oi1; }
}

// ============ merged prep v2: wave = one 1KB frag tile, fully coalesced writes ============
__global__ void prep_all_kernel(const float* __restrict__ W, const float* __restrict__ hidden,
                                unsigned short* __restrict__ wsW, unsigned short* __restrict__ wsA) {
    const int bw = threadIdx.x >> 6, l = threadIdx.x & 63;
    if (blockIdx.x < 160) {
        int t = blockIdx.x * 4 + bw;             // 0..639
        int o   = (t >> 4) * 16 + (l & 15);
        int col = (t & 15) * 32 + (l >> 4) * 8;
        const float* src = W + ((size_t)o << 9) + col;
        f32x4 a = *(const f32x4*)(src);
        f32x4 b = *(const f32x4*)(src + 4);
        *(s16x8*)(wsW + ((size_t)t << 9) + (l << 3)) = pack8v(a, b);
    } else {
        int t = (blockIdx.x - 160) * 4 + bw;     // 0..32767
        int row = (t >> 4) * 16 + (l & 15);
        int col = (t & 15) * 32 + (l >> 4) * 8;
        const float* src = hidden + ((size_t)row << 9) + col;
        f32x4 a = *(const f32x4*)(src);
        f32x4 b = *(const f32x4*)(src + 4);
        *(s16x8*)(wsA + ((size_t)t << 9) + (l << 3)) = pack8v(a, b);
    }
}

// ============ K1: barrier-free, LDS-free GEMM. 2048 blocks x 256 thr (r19: more TLP). ====
// 4 waves = 2 rg x 2 cg; per wave 32 rows (2 rf) x 80 cols (5 cf), acc 40 f32 — same
// per-wave plan as r17, but 8 blocks/CU (vs 2) to hide L2 frag-load latency.
// XCD swizzle: 4 ct-partners of one mt share an XCD (A chunks L2-hit 3 of 4 times).
__global__ __launch_bounds__(256, 4) void k1_gemm(
    const unsigned short* __restrict__ wsW,
    const unsigned short* __restrict__ wsA,
    const float* __restrict__ bias,
    unsigned short* __restrict__ lgout)
{
    const int tid = threadIdx.x;
    const int w = tid >> 6, lane = tid & 63;
    const int rg = w >> 1, cg = w & 1;
    const int q = lane >> 4, c = lane & 15;
    const int d = blockIdx.x;
    const int mt = (d & 7) * 64 + (d >> 5);   // 0..511 (64-row tiles); partners share d&7
    const int ct = (d >> 3) & 3;

    const unsigned short* a0p = wsA + ((size_t)(mt * 4 + rg * 2 + 0) << 13) + (lane << 3);
    const unsigned short* a1p = wsA + ((size_t)(mt * 4 + rg * 2 + 1) << 13) + (lane << 3);
    const unsigned short* wp  = wsW + ((size_t)(ct * 10 + cg * 5) << 13) + (lane << 3);

    f32x4 acc0[5], acc1[5];
#pragma unroll
    for (int cf = 0; cf < 5; ++cf) { acc0[cf] = (f32x4){0,0,0,0}; acc1[cf] = (f32x4){0,0,0,0}; }

    s16x8 Aa0, Aa1, Aw0, Aw1, Aw2, Aw3, Aw4;
    s16x8 Ba0, Ba1, Bw0, Bw1, Bw2, Bw3, Bw4;

#define LD(S, KK) { \
        S##a0 = *(const s16x8*)(a0p + (KK) * 512); \
        S##a1 = *(const s16x8*)(a1p + (KK) * 512); \
        S##w0 = *(const s16x8*)(wp + 0 * 8192 + (KK) * 512); \
        S##w1 = *(const s16x8*)(wp + 1 * 8192 + (KK) * 512); \
        S##w2 = *(const s16x8*)(wp + 2 * 8192 + (KK) * 512); \
        S##w3 = *(const s16x8*)(wp + 3 * 8192 + (KK) * 512); \
        S##w4 = *(const s16x8*)(wp + 4 * 8192 + (KK) * 512); }
#define MM(S) { \
        acc0[0] = __builtin_amdgcn_mfma_f32_16x16x32_bf16(S##a0, S##w0, acc0[0], 0, 0, 0); \
        acc1[0] = __builtin_amdgcn_mfma_f32_16x16x32_bf16(S##a1, S##w0, acc1[0], 0, 0, 0); \
        acc0[1] = __builtin_amdgcn_mfma_f32_16x16x32_bf16(S##a0, S##w1, acc0[1], 0, 0, 0); \
        acc1[1] = __builtin_amdgcn_mfma_f32_16x16x32_bf16(S##a1, S##w1, acc1[1], 0, 0, 0); \
        acc0[2] = __builtin_amdgcn_mfma_f32_16x16x32_bf16(S##a0, S##w2, acc0[2], 0, 0, 0); \
        acc1[2] = __builtin_amdgcn_mfma_f32_16x16x32_bf16(S##a1, S##w2, acc1[2], 0, 0, 0); \
        acc0[3] = __builtin_amdgcn_mfma_f32_16x16x32_bf16(S##a0, S##w3, acc0[3], 0, 0, 0); \
        acc1[3] = __builtin_amdgcn_mfma_f32_16x16x32_bf16(S##a1, S##w3, acc1[3], 0, 0, 0); \
        acc0[4] = __builtin_amdgcn_mfma_f32_16x16x32_bf16(S##a0, S##w4, acc0[4], 0, 0, 0); \
        acc1[4] = __builtin_amdgcn_mfma_f32_16x16x32_bf16(S##a1, S##w4, acc1[4], 0, 0, 0); }

    LD(A, 0)
#pragma unroll 1
    for (int kp = 0; kp < 8; ++kp) {
        LD(B, 2 * kp + 1)
        MM(A)
        if (kp < 7) LD(A, 2 * kp + 2)
        MM(B)
    }
#undef LD
#undef MM

    float bv[5];
#pragma unroll
    for (int cf = 0; cf < 5; ++cf) bv[cf] = bias[ct * 160 + cg * 80 + cf * 16 + c];
#pragma unroll
    for (int rf = 0; rf < 2; ++rf) {
        size_t mrow = (size_t)mt * 64 + rg * 32 + rf * 16 + q * 4;
        unsigned short* op = lgout + mrow * GV_ + ct * 160 + cg * 80 + c;
        const f32x4* ac = rf ? acc1 : acc0;
#pragma unroll
        for (int cf = 0; cf < 5; ++cf)
#pragma unroll
            for (int r = 0; r < 4; ++r)
                op[(size_t)r * GV_ + cf * 16] = f2bf(ac[cf][r] + bv[cf]);
    }
}

// ============ K2: 2048 blocks (one l) x 256 thr (4 waves). Wave = 4 b-rows. ============
__global__ __launch_bounds__(256, 4) void k2_epi(
    const float* __restrict__ hidden,
    const float* __restrict__ W,
    const float* __restrict__ bias,
    const float* __restrict__ cb,
    const float* __restrict__ gn,
    const unsigned short* __restrict__ lgb,
    float* __restrict__ out)
{
    __shared__ float PERPW[4][GV_];    // 10.2 KB
    const int tid = threadIdx.x;
    const int w = tid >> 6, lane = tid & 63;
    const int h = lane >> 5, k = lane & 31;
    const int l = blockIdx.x;

    f32x4 pac0 = {0,0,0,0}, pac1 = {0,0,0,0}, pac2 = {0,0,0,0};

    f32x4 Alg0, Alg1, Alg2, Agv0, Agv1, Agv2;
    f32x4 Blg0, Blg1, Blg2, Bgv0, Bgv1, Bgv2;

#define NTL(p) __builtin_nontemporal_load((const f32x4*)(p))
#define LOADROW(S, RR) { \
        size_t row_ = ((size_t)(w * 4 + (RR))) * L_ + l; \
        const unsigned short* lrb = lgb + row_ * GV_ + h * V_ + (k << 2); \
        const float* grb = gn + row_ * GV_ + h * V_ + (k << 2); \
        u16x4 L0 = *(const u16x4*)(lrb); \
        u16x4 L1 = *(const u16x4*)(lrb + 128); \
        S##gv0 = NTL(grb); S##gv1 = NTL(grb + 128); \
        _Pragma("unroll") \
        for (int j = 0; j < 4; ++j) { S##lg0[j] = bf2f(L0[j]); S##lg1[j] = bf2f(L1[j]); } \
        if (k < 16) { \
            u16x4 L2 = *(const u16x4*)(lrb + 256); \
            S##gv2 = NTL(grb + 256); \
            _Pragma("unroll") \
            for (int j = 0; j < 4; ++j) S##lg2[j] = bf2f(L2[j]); \
        } }

#define EXACT(CI, EN) { \
        if (EN) { \
            const int ci_ = (CI); \
            const float* ar_ = hidden + row_ * D1_ + (k << 4); \
            const float* wr_ = W + (size_t)(h * V_ + ci_) * D1_ + (k << 4); \
            double s_ = 0.0; \
            _Pragma("unroll 4") \
            for (int j = 0; j < 16; ++j) s_ = fma((double)ar_[j], (double)wr_[j], s_); \
            _Pragma("unroll") \
            for (int off = 1; off <= 16; off <<= 1) s_ += __shfl_xor(s_, off); \
            s_ += (double)bias[h * V_ + ci_] + (double)gn[row_ * GV_ + h * V_ + ci_]; \
            if (s_ > bestv || (s_ == bestv && ci_ < bi)) { bestv = s_; bi = ci_; } \
        } }

#define PROCROW(S, RR) { \
        const size_t row_ = ((size_t)(w * 4 + (RR))) * L_ + l; \
        _Pragma("unroll") \
        for (int j = 0; j < 4; ++j) { S##gv0[j] += S##lg0[j]; S##gv1[j] += S##lg1[j]; } \
        if (k < 16) { _Pragma("unroll") for (int j = 0; j < 4; ++j) S##gv2[j] += S##lg2[j]; } \
        float m1 = -3e38f; \
        _Pragma("unroll") \
        for (int j = 0; j < 4; ++j) { m1 = fmaxf(m1, S##gv0[j]); m1 = fmaxf(m1, S##gv1[j]); } \
        if (k < 16) { _Pragma("unroll") for (int j = 0; j < 4; ++j) m1 = fmaxf(m1, S##gv2[j]); } \
        _Pragma("unroll") \
        for (int mk = 1; mk <= 16; mk <<= 1) m1 = fmaxf(m1, __shfl_xor(m1, mk)); \
        int li = 0x7fffffff; \
        _Pragma("unroll") \
        for (int j = 0; j < 4; ++j) { \
            if (S##gv0[j] == m1) li = min(li, (k << 2) + j); \
            if (S##gv1[j] == m1) li = min(li, ((k + 32) << 2) + j); } \
        if (k < 16) { _Pragma("unroll") for (int j = 0; j < 4; ++j) if (S##gv2[j] == m1) li = min(li, ((k + 64) << 2) + j); } \
        _Pragma("unroll") \
        for (int mk = 1; mk <= 16; mk <<= 1) li = min(li, __shfl_xor(li, mk)); \
        const int i1 = li; \
        float m2 = -3e38f; \
        _Pragma("unroll") \
        for (int j = 0; j < 4; ++j) { \
            if (((k << 2) + j) != i1)        m2 = fmaxf(m2, S##gv0[j]); \
            if ((((k + 32) << 2) + j) != i1) m2 = fmaxf(m2, S##gv1[j]); } \
        if (k < 16) { _Pragma("unroll") for (int j = 0; j < 4; ++j) if ((((k + 64) << 2) + j) != i1) m2 = fmaxf(m2, S##gv2[j]); } \
        _Pragma("unroll") \
        for (int mk = 1; mk <= 16; mk <<= 1) m2 = fmaxf(m2, __shfl_xor(m2, mk)); \
        float se = 0.f; \
        _Pragma("unroll") \
        for (int j = 0; j < 4; ++j) { \
            S##lg0[j] = __expf(S##lg0[j]); se += S##lg0[j]; \
            S##lg1[j] = __expf(S##lg1[j]); se += S##lg1[j]; } \
        if (k < 16) { _Pragma("unroll") for (int j = 0; j < 4; ++j) { S##lg2[j] = __expf(S##lg2[j]); se += S##lg2[j]; } } \
        _Pragma("unroll") \
        for (int mk = 1; mk <= 16; mk <<= 1) se += __shfl_xor(se, mk); \
        const float inv = 1.0f / (se * 16.0f); \
        _Pragma("unroll") \
        for (int j = 0; j < 4; ++j) { pac0[j] += S##lg0[j] * inv; pac1[j] += S##lg1[j] * inv; } \
        if (k < 16) { _Pragma("unroll") for (int j = 0; j < 4; ++j) pac2[j] += S##lg2[j] * inv; } \
        int idx = i1; \
        if (m1 - m2 < THR_) { \
            int li2 = 0x7fffffff; \
            _Pragma("unroll") \
            for (int j = 0; j < 4; ++j) { \
                int v0 = (k << 2) + j;        if (v0 != i1 && S##gv0[j] == m2) li2 = min(li2, v0); \
                int v1 = ((k + 32) << 2) + j; if (v1 != i1 && S##gv1[j] == m2) li2 = min(li2, v1); } \
            if (k < 16) { _Pragma("unroll") for (int j = 0; j < 4; ++j) { int v2 = ((k + 64) << 2) + j; if (v2 != i1 && S##gv2[j] == m2) li2 = min(li2, v2); } } \
            _Pragma("unroll") \
            for (int mk = 1; mk <= 16; mk <<= 1) li2 = min(li2, __shfl_xor(li2, mk)); \
            const int i2 = li2; \
            float m3 = -3e38f; \
            _Pragma("unroll") \
            for (int j = 0; j < 4; ++j) { \
                int v0 = (k << 2) + j;        if (v0 != i1 && v0 != i2) m3 = fmaxf(m3, S##gv0[j]); \
                int v1 = ((k + 32) << 2) + j; if (v1 != i1 && v1 != i2) m3 = fmaxf(m3, S##gv1[j]); } \
            if (k < 16) { _Pragma("unroll") for (int j = 0; j < 4; ++j) { int v2 = ((k + 64) << 2) + j; if (v2 != i1 && v2 != i2) m3 = fmaxf(m3, S##gv2[j]); } } \
            _Pragma("unroll") \
            for (int mk = 1; mk <= 16; mk <<= 1) m3 = fmaxf(m3, __shfl_xor(m3, mk)); \
            int li3 = 0x7fffffff; \
            _Pragma("unroll") \
            for (int j = 0; j < 4; ++j) { \
                int v0 = (k << 2) + j;        if (v0 != i1 && v0 != i2 && S##gv0[j] == m3) li3 = min(li3, v0); \
                int v1 = ((k + 32) << 2) + j; if (v1 != i1 && v1 != i2 && S##gv1[j] == m3) li3 = min(li3, v1); } \
            if (k < 16) { _Pragma("unroll") for (int j = 0; j < 4; ++j) { int v2 = ((k + 64) << 2) + j; if (v2 != i1 && v2 != i2 && S##gv2[j] == m3) li3 = min(li3, v2); } } \
            _Pragma("unroll") \
            for (int mk = 1; mk <= 16; mk <<= 1) li3 = min(li3, __shfl_xor(li3, mk)); \
            const int i3 = li3; \
            double bestv = -1e300; int bi = 0; \
            EXACT(i1, true) \
            EXACT(i2, true) \
            EXACT(i3, (m1 - m3 < THR_)) \
            idx = bi; \
        } \
        { \
            const float* src = cb + (size_t)(h * V_ + idx) * DG_ + (k << 2); \
            float* dst = out + row_ * (G_ * DG_) + h * DG_ + (k << 2); \
            __builtin_nontemporal_store(*(const f32x4*)(src),       (f32x4*)(dst)); \
            __builtin_nontemporal_store(*(const f32x4*)(src + 128), (f32x4*)(dst + 128)); \
            __builtin_nontemporal_store(*(const f32x4*)(src + 256), (f32x4*)(dst + 256)); \
        } }

    LOADROW(A, 0)
    LOADROW(B, 1)
    PROCROW(A, 0)
    LOADROW(A, 2)
    PROCROW(B, 1)
    LOADROW(B, 3)
    PROCROW(A, 2)
    PROCROW(B, 3)
#undef NTL
#undef LOADROW
#undef EXACT
#undef PROCROW

    *(f32x4*)&PERPW[w][h * V_ + (k << 2)]        = pac0;
    *(f32x4*)&PERPW[w][h * V_ + ((k + 32) << 2)] = pac1;
    if (k < 16)
        *(f32x4*)&PERPW[w][h * V_ + ((k + 64) << 2)] = pac2;
    __syncthreads();

    if (tid < 160) {
        f32x4 s = *(const f32x4*)&PERPW[0][tid * 4];
#pragma unroll
        for (int ww = 1; ww < 4; ++ww) {
            f32x4 t = *(const f32x4*)&PERPW[ww][tid * 4];
#pragma unroll
            for (int j = 0; j < 4; ++j) s[j] += t[j];
        }
        __builtin_nontemporal_store(s, (f32x4*)(out + OUT0_ + (size_t)l * GV_ + tid * 4));
    }
}

// ============ Fallback: fused kernel (ws too small for split planes) ============
template<bool HAS_WS>
__global__ __launch_bounds__(512, 4) void gvq7_kernel(
    const float* __restrict__ hidden,
    const float* __restrict__ W,
    const float* __restrict__ bias,
    const float* __restrict__ cb,
    const float* __restrict__ gn,
    float* __restrict__ out,
    const unsigned short* __restrict__ ws)
{
    __shared__ float GLDS[32][GPAD_];
    __shared__ __align__(16) float pm1[4][64], pm2[4][64], plx[4][64], psum[4][64];
    __shared__ __align__(16) int   pi1[4][64], pi2[4][64];
    __shared__ int IDX[64];
    __shared__ int qn, qrow[64], qc1[64], qc2[64];

    const int tid  = threadIdx.x;
    const int w    = tid >> 6, lane = tid & 63;
    const int rg   = w >> 2, cg = w & 3;
    const int q    = lane >> 4, c = lane & 15;
    const int d    = blockIdx.x;
    const int g    = (d >> 3) & 1;
    const int lq   = (d >> 4) * 8 + (d & 7);
    const size_t lbase = (size_t)lq * 4;

    if (tid == 0) qn = 0;

    const int arow = lane & 15;
    const int kq8  = (lane >> 4) * 8;
    const float* aP0 = hidden + ((size_t)arow * L_ + lbase + rg * 2) * D1_ + kq8;
    const float* aP1 = aP0 + D1_;
    const unsigned short* wP = ws + (size_t)(g * 20 + cg * 5) * 8192 + (size_t)lane * 8;
    const float* wfP = W + ((size_t)(g * V_ + cg * 80 + arow)) * D1_ + kq8;

    const int srow = tid >> 4, t16 = tid & 15;
    const float* gnst = gn + (((size_t)(srow & 15) * L_ + lbase + ((srow >> 4) << 1)) * G_ + g) * V_
                           + (t16 << 2);

    f32x4 acc0[5], acc1[5];
#pragma unroll
    for (int cf = 0; cf < 5; ++cf) { acc0[cf] = (f32x4){0,0,0,0}; acc1[cf] = (f32x4){0,0,0,0}; }

    float4 Aa0, Aa1, Aa2, Aa3, Ba0, Ba1, Ba2, Ba3;
    s16x8 Aw0, Aw1, Aw2, Aw3, Aw4, Bw0, Bw1, Bw2, Bw3, Bw4;
    s16x8 fA0, fA1, fB0, fB1;

#define LDA(S, R) { S##a0 = *(const float4*)(aP0 + (R)*32);     S##a1 = *(const float4*)(aP0 + (R)*32 + 4); \
                    S##a2 = *(const float4*)(aP1 + (R)*32);     S##a3 = *(const float4*)(aP1 + (R)*32 + 4); }
#define LDW1(S, CF, R) { if (HAS_WS) { S##w##CF = *(const s16x8*)(wP + (CF)*8192 + (R)*512); } \
                         else { float4 x_ = *(const float4*)(wfP + (CF)*8192 + (R)*32); \
                                float4 y_ = *(const float4*)(wfP + (CF)*8192 + (R)*32 + 4); \
                                S##w##CF = pack8(x_, y_); } }
#define LDW(S, R) { LDW1(S,0,R) LDW1(S,1,R) LDW1(S,2,R) LDW1(S,3,R) LDW1(S,4,R) }
#define CVT(S) { f##S##0 = pack8(S##a0, S##a1); f##S##1 = pack8(S##a2, S##a3); }
#define MM1(S, CF) { acc0[CF] = __builtin_amdgcn_mfma_f32_16x16x32_bf16(f##S##0, S##w##CF, acc0[CF], 0, 0, 0); \
                     acc1[CF] = __builtin_amdgcn_mfma_f32_16x16x32_bf16(f##S##1, S##w##CF, acc1[CF], 0, 0, 0); }
#define MM(S) { MM1(S,0) MM1(S,1) MM1(S,2) MM1(S,3) MM1(S,4) }

    LDA(A, 0) LDW(A, 0)
#pragma unroll 1
    for (int kp = 0; kp < 8; ++kp) {
        CVT(A)
        LDA(B, 1) LDW(B, 1)
        MM(A)
        CVT(B)
        if (kp < 7) { LDA(A, 2) LDW(A, 2) }
        MM(B)
        aP0 += 64; aP1 += 64; wP += 1024; wfP += 64;
    }
#undef LDA
#undef LDW1
#undef LDW
#undef CVT
#undef MM1
#undef MM

    float bv[5];
#pragma unroll
    for (int cf = 0; cf < 5; ++cf) bv[cf] = bias[g * V_ + cg * 80 + cf * 16 + c];
#pragma unroll
    for (int cf = 0; cf < 5; ++cf)
#pragma unroll
        for (int r = 0; r < 4; ++r) { acc0[cf][r] += bv[cf]; acc1[cf][r] += bv[cf]; }

    auto scanrf = [&](const f32x4* a5, int rf) {
        float m1[4], m2[4], lx[4]; int i1[4], i2[4];
#pragma unroll
        for (int r = 0; r < 4; ++r) { m1[r] = -3e38f; m2[r] = -3e38f; lx[r] = -3e38f; i1[r] = 0; i2[r] = 0; }
#pragma unroll
        for (int cf = 0; cf < 5; ++cf) {
            const int col = cg * 80 + cf * 16 + c;
#pragma unroll
            for (int r = 0; r < 4; ++r) {
                float lg = a5[cf][r];
                float s  = lg + GLDS[rg * 16 + q * 4 + r][col];
                lx[r] = fmaxf(lx[r], lg);
                if (s > m1[r])      { m2[r] = m1[r]; i2[r] = i1[r]; m1[r] = s; i1[r] = col; }
                else if (s > m2[r]) { m2[r] = s; i2[r] = col; }
            }
        }
#pragma unroll
        for (int mk = 1; mk <= 8; mk <<= 1) {
#pragma unroll
            for (int r = 0; r < 4; ++r) {
                float om1 = __shfl_xor(m1[r], mk); int oi1 = __shfl_xor(i1[r], mk);
                float om2 = __shfl_xor(m2[r], mk); int oi2 = __shfl_xor(i2[r], mk);
                lx[r] = fmaxf(lx[r], __shfl_xor(lx[r], mk));
                merge2(m1[r], i1[r], m2[r], i2[r], om1, oi1, om2, oi2);
            }
        }
        if (c == 0) {
            int row0 = rg * 32 + rf * 16 + q * 4;
            *(f32x4*)&pm1[cg][row0] = (f32x4){m1[0], m1[1], m1[2], m1[3]};
            *(s32x4*)&pi1[cg][row0] = (s32x4){i1[0], i1[1], i1[2], i1[3]};
            *(f32x4*)&pm2[cg][row0] = (f32x4){m2[0], m2[1], m2[2], m2[3]};
            *(s32x4*)&pi2[cg][row0] = (s32x4){i2[0], i2[1], i2[2], i2[3]};
            *(f32x4*)&plx[cg][row0] = (f32x4){lx[0], lx[1], lx[2], lx[3]};
        }
    };

    {
        f32x4 gr[5];
#pragma unroll
        for (int j = 0; j < 5; ++j)
            gr[j] = __builtin_nontemporal_load((const f32x4*)(gnst + j * 64));
#pragma unroll
        for (int j = 0; j < 5; ++j)
            *(f32x4*)&GLDS[srow][(t16 << 2) + j * 64] = gr[j];
        __syncthreads();
        scanrf(acc0, 0);
        __syncthreads();
    }
    {
        f32x4 gr[5];
#pragma unroll
        for (int j = 0; j < 5; ++j)
            gr[j] = __builtin_nontemporal_load((const f32x4*)(gnst + GV_ + j * 64));
#pragma unroll
        for (int j = 0; j < 5; ++j)
            *(f32x4*)&GLDS[srow][(t16 << 2) + j * 64] = gr[j];
        __syncthreads();
        scanrf(acc1, 1);
        __syncthreads();
    }

    auto softrf = [&](f32x4* a5, int rf) {
        int row0 = rg * 32 + rf * 16 + q * 4;
        float LM[4], se[4];
#pragma unroll
        for (int r = 0; r < 4; ++r) {
            LM[r] = fmaxf(fmaxf(plx[0][row0 + r], plx[1][row0 + r]),
                          fmaxf(plx[2][row0 + r], plx[3][row0 + r]));
            se[r] = 0.f;
        }
#pragma unroll
        for (int cf = 0; cf < 5; ++cf)
#pragma unroll
            for (int r = 0; r < 4; ++r) {
                float e = __expf(a5[cf][r] - LM[r]);
                a5[cf][r] = e; se[r] += e;
            }
#pragma unroll
        for (int mk = 1; mk <= 8; mk <<= 1)
#pragma unroll
            for (int r = 0; r < 4; ++r) se[r] += __shfl_xor(se[r], mk);
        if (c == 0) *(f32x4*)&psum[cg][row0] = (f32x4){se[0], se[1], se[2], se[3]};
    };
    softrf(acc0, 0);
    softrf(acc1, 1);
    __syncthreads();

    auto perprf = [&](const f32x4* a5, int rf) {
        int row0 = rg * 32 + rf * 16 + q * 4;
        float IZ[4];
#pragma unroll
        for (int r = 0; r < 4; ++r)
            IZ[r] = 1.0f / ((psum[0][row0 + r] + psum[1][row0 + r]
                           + psum[2][row0 + r] + psum[3][row0 + r]) * 16.0f);
        size_t ob = OUT0_ + (lbase + rg * 2 + rf) * GV_ + g * V_ + cg * 80 + c;
#pragma unroll
        for (int cf = 0; cf < 5; ++cf) {
            float pp = a5[cf][0] * IZ[0] + a5[cf][1] * IZ[1]
                     + a5[cf][2] * IZ[2] + a5[cf][3] * IZ[3];
            pp += __shfl_xor(pp, 16); pp += __shfl_xor(pp, 32);
            if (q == 0) __builtin_nontemporal_store(pp, &out[ob + cf * 16]);
        }
    };
    perprf(acc0, 0);
    perprf(acc1, 1);

    if (tid < 64) {
        const int row = tid;
        float M1 = pm1[0][row]; int I1 = pi1[0][row];
        float M2 = pm2[0][row]; int I2 = pi2[0][row];
#pragma unroll
        for (int c2 = 1; c2 < 4; ++c2)
            merge2(M1, I1, M2, I2, pm1[c2][row], pi1[c2][row], pm2[c2][row], pi2[c2][row]);
        if (M1 - M2 >= 8e-3f) {
            IDX[row] = I1;
        } else {
            int s = atomicAdd(&qn, 1);
            qrow[s] = row; qc1[s] = I1; qc2[s] = I2;
        }
    }
    __syncthreads();

    {
        const int nq = qn;
        for (int qi = w; qi < nq; qi += 8) {
            const int row = qrow[qi];
            const int c1 = qc1[qi], c2 = qc2[qi];
            const int b = row & 15, li = row >> 4;
            const float* ar = hidden + ((size_t)b * L_ + lbase + li) * D1_ + lane * 8;
            const float* w1 = W + (size_t)(g * V_ + c1) * D1_ + lane * 8;
            const float* w2 = W + (size_t)(g * V_ + c2) * D1_ + lane * 8;
            double s1 = 0.0, s2 = 0.0;
#pragma unroll
            for (int j = 0; j < 8; ++j) {
                double a = (double)ar[j];
                s1 = fma(a, (double)w1[j], s1);
                s2 = fma(a, (double)w2[j], s2);
            }
#pragma unroll
            for (int off = 1; off < 64; off <<= 1) {
                s1 += __shfl_xor(s1, off);
                s2 += __shfl_xor(s2, off);
            }
            if (lane == 0) {
                const size_t gb = (((size_t)b * L_ + lbase + li) * G_ + g) * V_;
                s1 += (double)bias[g * V_ + c1] + (double)gn[gb + c1];
                s2 += (double)bias[g * V_ + c2] + (double)gn[gb + c2];
                IDX[row] = (s2 > s1 || (s2 == s1 && c2 < c1)) ? c2 : c1;
            }
        }
    }
    __syncthreads();

#pragma unroll 1
    for (int it = 0; it < 12; ++it) {
        int i = tid + it * 512;
        int row = i / 96, f = i - row * 96;
        int v = IDX[row];
        int b = row & 15, li = row >> 4;
        f32x4 val = *(const f32x4*)(cb + ((size_t)(g * V_ + v) * DG_) + f * 4);
        __builtin_nontemporal_store(val,
            (f32x4*)(out + ((size_t)b * L_ + lbase + li) * (G_ * DG_) + g * DG_ + f * 4));
    }
}

extern "C" void kernel_launch(void* const* d_in, const int* in_sizes, int n_in,
                              void* d_out, int out_size, void* d_ws, size_t ws_size,
                              hipStream_t stream) {
    const float* hidden   = (const float*)d_in[0];
    const float* W        = (const float*)d_in[1];
    const float* bias     = (const float*)d_in[2];
    const float* codebook = (const float*)d_in[3];
    const float* gumbel   = (const float*)d_in[4];
    float* out = (float*)d_out;

    if (ws_size >= SPLIT2_WS_) {
        unsigned short* wsW = (unsigned short*)d_ws;
        unsigned short* wsA = wsW + WSA_OFF_SH_;
        unsigned short* lgb = wsW + LG_OFF_SH_;
        prep_all_kernel<<<160 + 8192, 256, 0, stream>>>(W, hidden, wsW, wsA);
        k1_gemm<<<2048, 256, 0, stream>>>(wsW, wsA, bias, lgb);
        k2_epi<<<2048, 256, 0, stream>>>(hidden, W, bias, codebook, gumbel, lgb, out);
    } else if (ws_size >= WS_BYTES_) {
        prep_all_kernel<<<160, 256, 0, stream>>>(W, hidden, (unsigned short*)d_ws, nullptr);
        gvq7_kernel<true><<<1024, 512, 0, stream>>>(hidden, W, bias, codebook, gumbel, out,
                                                    (const unsigned short*)d_ws);
    } else {
        gvq7_kernel<false><<<1024, 512, 0, stream>>>(hidden, W, bias, codebook, gumbel, out,
                                                     (const unsigned short*)d_ws);
    }
}